// Round 1
// baseline (2184.878 us; speedup 1.0000x reference)
//
#include <hip/hip_runtime.h>
#include <stdint.h>

// Problem geometry (fixed by the reference)
#define M_TOTAL 8192     // B*S = 4*2048
#define N_TOTAL 16384    // D_OUT
#define K_TOTAL 4096     // D_IN

// GEMM tiling (m97 ladder-step-3 structure: 128x128 tile, BK=32, 4 waves)
#define BM 128
#define BN 128
#define BK 32

typedef __attribute__((ext_vector_type(8))) short short8;   // 8 bf16 (4 VGPRs)
typedef __attribute__((ext_vector_type(4))) float floatx4;  // MFMA C/D fragment

// ---------------------------------------------------------------------------
// f32 -> bf16 with round-to-nearest-even (no NaN inputs in this problem)
__device__ __forceinline__ unsigned short f2bf(float f) {
    union { float f; uint32_t u; } v; v.f = f;
    uint32_t u = v.u;
    return (unsigned short)((u + 0x7fffu + ((u >> 16) & 1u)) >> 16);
}

// ---------------------------------------------------------------------------
// Pre-pass 1: x[M][K] f32 -> bf16 (vectorized: 8 elems / thread / iter)
__global__ void convert_x_kernel(const float* __restrict__ x,
                                 unsigned short* __restrict__ o, int n8) {
    int idx = blockIdx.x * blockDim.x + threadIdx.x;
    int stride = gridDim.x * blockDim.x;
    for (int i = idx; i < n8; i += stride) {
        const float4* p = (const float4*)x + (size_t)i * 2;
        float4 a = p[0], b = p[1];
        ushort4 r0, r1;
        r0.x = f2bf(a.x); r0.y = f2bf(a.y); r0.z = f2bf(a.z); r0.w = f2bf(a.w);
        r1.x = f2bf(b.x); r1.y = f2bf(b.y); r1.z = f2bf(b.z); r1.w = f2bf(b.w);
        ushort4* po = (ushort4*)o + (size_t)i * 2;
        po[0] = r0; po[1] = r1;
    }
}

// Pre-pass 2: w[N][K] = scale*(q - zp), int32 -> bf16 (8 elems / thread / iter)
__global__ void convert_w_kernel(const int* __restrict__ q,
                                 const float* __restrict__ scale,
                                 const float* __restrict__ zp,
                                 unsigned short* __restrict__ o, int n8) {
    const float s = scale[0];
    const float z = zp[0];
    int idx = blockIdx.x * blockDim.x + threadIdx.x;
    int stride = gridDim.x * blockDim.x;
    for (int i = idx; i < n8; i += stride) {
        const int4* p = (const int4*)q + (size_t)i * 2;
        int4 a = p[0], b = p[1];
        ushort4 r0, r1;
        r0.x = f2bf(s * ((float)a.x - z)); r0.y = f2bf(s * ((float)a.y - z));
        r0.z = f2bf(s * ((float)a.z - z)); r0.w = f2bf(s * ((float)a.w - z));
        r1.x = f2bf(s * ((float)b.x - z)); r1.y = f2bf(s * ((float)b.y - z));
        r1.z = f2bf(s * ((float)b.z - z)); r1.w = f2bf(s * ((float)b.w - z));
        ushort4* po = (ushort4*)o + (size_t)i * 2;
        po[0] = r0; po[1] = r1;
    }
}

// ---------------------------------------------------------------------------
// Main GEMM: C[m][n] = sum_k A[m][k] * Bt[n][k]  (+ bias[n])
// A: [M][K] bf16 row-major, Bt: [N][K] bf16 row-major (both K-contiguous).
// 128x128 tile, BK=32, 256 threads = 4 waves in 2x2, each wave 64x64 (4x4
// mfma_f32_16x16x32_bf16 fragments). global_load_lds width-16 staging,
// 2-barrier K-loop (m97 structure, ~870-910 TF verified on gfx950).
__global__ void gemm_bf16_bt(const unsigned short* __restrict__ A,
                             const unsigned short* __restrict__ Bt,
                             const float* __restrict__ bias,
                             float* __restrict__ C) {
    __shared__ __align__(16) unsigned short As[BM * BK];  // 8 KB
    __shared__ __align__(16) unsigned short Bs[BN * BK];  // 8 KB

    const int tid  = threadIdx.x;
    const int lane = tid & 63;
    const int wave = tid >> 6;
    const int wm = wave >> 1;   // 0..1
    const int wn = wave & 1;    // 0..1

    const int blockRow = blockIdx.y * BM;
    const int blockCol = blockIdx.x * BN;

    const unsigned short* Ab = A  + (size_t)blockRow * K_TOTAL;
    const unsigned short* Bb = Bt + (size_t)blockCol * K_TOTAL;

    floatx4 acc[4][4];
#pragma unroll
    for (int i = 0; i < 4; ++i)
#pragma unroll
        for (int j = 0; j < 4; ++j) acc[i][j] = (floatx4)0.0f;

    const int frag_row = lane & 15;        // m (or n) within fragment
    const int frag_k   = (lane >> 4) * 8;  // k sub-slice base

    for (int k0 = 0; k0 < K_TOTAL; k0 += BK) {
        // Stage A and B tiles (8 KB each) via direct global->LDS, 16 B/lane.
        // chunk c in [0,512): row = c/4, k-elems = (c%4)*8. LDS dest is
        // linear (base + lane*16) as global_load_lds requires.
#pragma unroll
        for (int it = 0; it < 2; ++it) {
            const int c   = it * 256 + tid;
            const int row = c >> 2;
            const int kel = (c & 3) * 8;
            const unsigned short* ga = Ab + (size_t)row * K_TOTAL + k0 + kel;
            const unsigned short* gb = Bb + (size_t)row * K_TOTAL + k0 + kel;
            __builtin_amdgcn_global_load_lds(
                (const __attribute__((address_space(1))) uint32_t*)ga,
                (__attribute__((address_space(3))) uint32_t*)(&As[c * 8]),
                16, 0, 0);
            __builtin_amdgcn_global_load_lds(
                (const __attribute__((address_space(1))) uint32_t*)gb,
                (__attribute__((address_space(3))) uint32_t*)(&Bs[c * 8]),
                16, 0, 0);
        }
        __syncthreads();   // drains vmcnt before barrier (compiler-inserted)

        short8 a[4], b[4];
#pragma unroll
        for (int mi = 0; mi < 4; ++mi)
            a[mi] = *(const short8*)&As[(wm * 64 + mi * 16 + frag_row) * BK + frag_k];
#pragma unroll
        for (int ni = 0; ni < 4; ++ni)
            b[ni] = *(const short8*)&Bs[(wn * 64 + ni * 16 + frag_row) * BK + frag_k];

#pragma unroll
        for (int mi = 0; mi < 4; ++mi)
#pragma unroll
            for (int ni = 0; ni < 4; ++ni)
                acc[mi][ni] = __builtin_amdgcn_mfma_f32_16x16x32_bf16(
                    a[mi], b[ni], acc[mi][ni], 0, 0, 0);

        __syncthreads();
    }

    // Epilogue: C/D layout col = lane&15, row = (lane>>4)*4 + reg (m89/m91).
    const int colBase = blockCol + wn * 64;
    const int rowBase = blockRow + wm * 64;
#pragma unroll
    for (int ni = 0; ni < 4; ++ni) {
        const int col = colBase + ni * 16 + (lane & 15);
        const float bv = bias[col];
#pragma unroll
        for (int mi = 0; mi < 4; ++mi) {
            const int row = rowBase + mi * 16 + (lane >> 4) * 4;
#pragma unroll
            for (int r = 0; r < 4; ++r)
                C[(size_t)(row + r) * N_TOTAL + col] = acc[mi][ni][r] + bv;
        }
    }
}

// ---------------------------------------------------------------------------
// Insurance fallback (only if ws_size < 201 MB): straightforward f32 tiled
// GEMM with inline dequant. Slow (~tens of ms) but correct.
#define FBM 64
#define FBN 64
#define FBK 16
__global__ void fallback_gemm(const float* __restrict__ x,
                              const int* __restrict__ q,
                              const float* __restrict__ scale,
                              const float* __restrict__ zp,
                              const float* __restrict__ bias,
                              float* __restrict__ C) {
    __shared__ float Xs[FBM][FBK];
    __shared__ float Ws[FBN][FBK];
    const float s = scale[0];
    const float z = zp[0];
    const int tid = threadIdx.x;
    const int blockRow = blockIdx.y * FBM;
    const int blockCol = blockIdx.x * FBN;
    const int tr = tid >> 4, tc = tid & 15;
    float acc[4][4] = {};
    for (int k0 = 0; k0 < K_TOTAL; k0 += FBK) {
#pragma unroll
        for (int i = 0; i < 4; ++i) {
            int c = i * 256 + tid;       // 0..1023
            int row = c >> 4, kk = c & 15;
            Xs[row][kk] = x[(size_t)(blockRow + row) * K_TOTAL + k0 + kk];
            Ws[row][kk] = s * ((float)q[(size_t)(blockCol + row) * K_TOTAL + k0 + kk] - z);
        }
        __syncthreads();
#pragma unroll
        for (int kk = 0; kk < FBK; ++kk) {
            float xv[4], wv[4];
#pragma unroll
            for (int i = 0; i < 4; ++i) xv[i] = Xs[tr * 4 + i][kk];
#pragma unroll
            for (int j = 0; j < 4; ++j) wv[j] = Ws[tc * 4 + j][kk];
#pragma unroll
            for (int i = 0; i < 4; ++i)
#pragma unroll
                for (int j = 0; j < 4; ++j) acc[i][j] += xv[i] * wv[j];
        }
        __syncthreads();
    }
#pragma unroll
    for (int i = 0; i < 4; ++i)
#pragma unroll
        for (int j = 0; j < 4; ++j) {
            int row = blockRow + tr * 4 + i;
            int col = blockCol + tc * 4 + j;
            C[(size_t)row * N_TOTAL + col] = acc[i][j] + bias[col];
        }
}

// ---------------------------------------------------------------------------
extern "C" void kernel_launch(void* const* d_in, const int* in_sizes, int n_in,
                              void* d_out, int out_size, void* d_ws, size_t ws_size,
                              hipStream_t stream) {
    const float* x     = (const float*)d_in[0];   // [4,2048,4096] f32
    const int*   qw    = (const int*)d_in[1];     // [16384,4096] i32
    const float* scale = (const float*)d_in[2];   // scalar
    const float* zp    = (const float*)d_in[3];   // scalar
    const float* bias  = (const float*)d_in[4];   // [16384] f32
    float* out = (float*)d_out;                   // [4,2048,16384] f32

    const size_t x_elems = (size_t)M_TOTAL * K_TOTAL;   // 33.5M
    const size_t w_elems = (size_t)N_TOTAL * K_TOTAL;   // 67.1M
    const size_t need = x_elems * 2 + w_elems * 2;      // 201 MB

    if (ws_size >= need) {
        unsigned short* xb = (unsigned short*)d_ws;
        unsigned short* wb = xb + x_elems;
        convert_x_kernel<<<2048, 256, 0, stream>>>(x, xb, (int)(x_elems / 8));
        convert_w_kernel<<<2048, 256, 0, stream>>>(qw, scale, zp, wb, (int)(w_elems / 8));
        dim3 grid(N_TOTAL / BN, M_TOTAL / BM);   // (128, 64)
        gemm_bf16_bt<<<grid, 256, 0, stream>>>(xb, wb, bias, out);
    } else {
        dim3 grid(N_TOTAL / FBN, M_TOTAL / FBM);
        fallback_gemm<<<grid, 256, 0, stream>>>(x, qw, scale, zp, bias, out);
    }
}